// Round 1
// baseline (667.007 us; speedup 1.0000x reference)
//
#include <hip/hip_runtime.h>
#include <hip/hip_bf16.h>

#define TT 128
#define LRELU(v) ((v) > 0.f ? (v) : 0.1f * (v))

// ---------------------------------------------------------------------------
// Fused conv1+conv2+conv3 (+BN+LeakyReLU) + adaptive pools -> ms[N][3328]
// One workgroup (256 threads) per sequence n. All intermediates in LDS.
// ---------------------------------------------------------------------------
__global__ __launch_bounds__(256) void conv_fused_kernel(
    const float* __restrict__ xg,                    // [N][128][6]
    const float* __restrict__ w1, const float* __restrict__ b1,
    const float* __restrict__ w2, const float* __restrict__ b2,
    const float* __restrict__ w3, const float* __restrict__ b3,
    const float* __restrict__ g1, const float* __restrict__ be1,
    const float* __restrict__ m1, const float* __restrict__ v1,
    const float* __restrict__ g2, const float* __restrict__ be2,
    const float* __restrict__ m2, const float* __restrict__ v2,
    const float* __restrict__ g3, const float* __restrict__ be3,
    const float* __restrict__ m3, const float* __restrict__ v3,
    float* __restrict__ ms)                          // [N][3328]
{
    __shared__ float sx[6][130];     // padded: col t+1 holds time t
    __shared__ float h1[64][130];
    __shared__ float h2[128][130];
    __shared__ float A1[64], C1[64], A2[128], C2[128], A3[256], C3[256];

    const int tid = threadIdx.x;
    const int n = blockIdx.x;

    // Fold BN: y = A*conv + C
    if (tid < 64)  { float a = g1[tid] * rsqrtf(v1[tid] + 1e-5f); A1[tid] = a; C1[tid] = (b1[tid] - m1[tid]) * a + be1[tid]; }
    if (tid < 128) { float a = g2[tid] * rsqrtf(v2[tid] + 1e-5f); A2[tid] = a; C2[tid] = (b2[tid] - m2[tid]) * a + be2[tid]; }
    { int c = tid; float a = g3[c] * rsqrtf(v3[c] + 1e-5f); A3[c] = a; C3[c] = (b3[c] - m3[c]) * a + be3[c]; }

    // Load x: [T][6] -> sx[c][t+1]
    const float* xrow = xg + (size_t)n * (TT * 6);
    #pragma unroll
    for (int i = 0; i < 3; ++i) {
        int idx = tid + i * 256;           // 0..767
        float vv = xrow[idx];
        int t = idx / 6, c = idx % 6;
        sx[c][t + 1] = vv;
    }
    if (tid < 6)   { sx[tid][0] = 0.f; sx[tid][129] = 0.f; }
    if (tid < 64)  { h1[tid][0] = 0.f; h1[tid][129] = 0.f; }
    if (tid < 128) { h2[tid][0] = 0.f; h2[tid][129] = 0.f; }
    __syncthreads();

    // ---- conv1: 6 -> 64.  Thread tile: 4 co x 8 t ----
    {
        int tIdx = tid & 15, cIdx = tid >> 4;     // 16 x 16
        int t0 = tIdx * 8, co0 = cIdx * 4;
        float acc[4][8];
        #pragma unroll
        for (int c = 0; c < 4; ++c)
            #pragma unroll
            for (int t = 0; t < 8; ++t) acc[c][t] = 0.f;
        for (int ci = 0; ci < 6; ++ci) {
            float hv[10];
            #pragma unroll
            for (int u = 0; u < 10; ++u) hv[u] = sx[ci][t0 + u];
            #pragma unroll
            for (int c = 0; c < 4; ++c) {
                const float* wp = w1 + ((size_t)(co0 + c) * 6 + ci) * 3;
                float wa = wp[0], wb = wp[1], wc = wp[2];
                #pragma unroll
                for (int t = 0; t < 8; ++t)
                    acc[c][t] = fmaf(wa, hv[t], fmaf(wb, hv[t + 1], fmaf(wc, hv[t + 2], acc[c][t])));
            }
        }
        #pragma unroll
        for (int c = 0; c < 4; ++c) {
            float a = A1[co0 + c], cc = C1[co0 + c];
            #pragma unroll
            for (int t = 0; t < 8; ++t) {
                float vv = fmaf(a, acc[c][t], cc);
                h1[co0 + c][t0 + t + 1] = LRELU(vv);
            }
        }
    }
    __syncthreads();

    // ---- conv2: 64 -> 128.  Thread tile: 4 co x 16 t ----
    {
        int tIdx = tid & 7, cIdx = tid >> 3;      // 8 x 32
        int t0 = tIdx * 16, co0 = cIdx * 4;
        float acc[4][16];
        #pragma unroll
        for (int c = 0; c < 4; ++c)
            #pragma unroll
            for (int t = 0; t < 16; ++t) acc[c][t] = 0.f;
        for (int ci = 0; ci < 64; ++ci) {
            float hv[18];
            #pragma unroll
            for (int u = 0; u < 18; ++u) hv[u] = h1[ci][t0 + u];
            #pragma unroll
            for (int c = 0; c < 4; ++c) {
                const float* wp = w2 + ((size_t)(co0 + c) * 64 + ci) * 3;
                float wa = wp[0], wb = wp[1], wc = wp[2];
                #pragma unroll
                for (int t = 0; t < 16; ++t)
                    acc[c][t] = fmaf(wa, hv[t], fmaf(wb, hv[t + 1], fmaf(wc, hv[t + 2], acc[c][t])));
            }
        }
        #pragma unroll
        for (int c = 0; c < 4; ++c) {
            float a = A2[co0 + c], cc = C2[co0 + c];
            #pragma unroll
            for (int t = 0; t < 16; ++t) {
                float vv = fmaf(a, acc[c][t], cc);
                h2[co0 + c][t0 + t + 1] = LRELU(vv);
            }
        }
    }
    __syncthreads();

    // ---- conv3: 128 -> 256 fused with pooling (no h3 materialization) ----
    {
        int tIdx = tid & 7, cIdx = tid >> 3;      // 8 t-groups x 32 c-groups
        int t0 = tIdx * 16;
        float* msrow = ms + (size_t)n * 3328;
        for (int p = 0; p < 2; ++p) {
            int co0 = cIdx * 4 + p * 128;
            float acc[4][16];
            #pragma unroll
            for (int c = 0; c < 4; ++c)
                #pragma unroll
                for (int t = 0; t < 16; ++t) acc[c][t] = 0.f;
            for (int ci = 0; ci < 128; ++ci) {
                float hv[18];
                #pragma unroll
                for (int u = 0; u < 18; ++u) hv[u] = h2[ci][t0 + u];
                #pragma unroll
                for (int c = 0; c < 4; ++c) {
                    const float* wp = w3 + ((size_t)(co0 + c) * 128 + ci) * 3;
                    float wa = wp[0], wb = wp[1], wc = wp[2];
                    #pragma unroll
                    for (int t = 0; t < 16; ++t)
                        acc[c][t] = fmaf(wa, hv[t], fmaf(wb, hv[t + 1], fmaf(wc, hv[t + 2], acc[c][t])));
                }
            }
            #pragma unroll
            for (int c = 0; c < 4; ++c) {
                int co = co0 + c;
                float a = A3[co], cc = C3[co];
                float s16 = 0.f;
                #pragma unroll
                for (int t = 0; t < 16; ++t) {
                    float vv = fmaf(a, acc[c][t], cc);
                    vv = LRELU(vv);
                    s16 += vv;
                }
                // local pool: this thread owns exactly bin tIdx for channel co
                msrow[co * 8 + tIdx] = s16 * (1.f / 16.f);
                // mid pool: pairs of adjacent tIdx (lanes differ in bit0)
                float s32 = s16 + __shfl_xor(s16, 1);
                if ((tIdx & 1) == 0) msrow[2048 + co * 4 + (tIdx >> 1)] = s32 * (1.f / 32.f);
                // global pool: reduce over the 8 lanes sharing cIdx
                float s128 = s32 + __shfl_xor(s32, 2);
                s128 += __shfl_xor(s128, 4);
                if (tIdx == 0) msrow[3072 + co] = s128 * (1.f / 128.f);
            }
        }
    }
}

// ---------------------------------------------------------------------------
// C[M][N] = act(A[M][K] x Bw[N][K]^T + bias).  64x64 block tile, 4x4/thread.
// ---------------------------------------------------------------------------
template <bool RELU>
__global__ __launch_bounds__(256) void gemm_bt_kernel(
    const float* __restrict__ A, const float* __restrict__ Bw,
    const float* __restrict__ bias, float* __restrict__ C,
    int M, int N, int K)
{
    __shared__ float As[64][33];
    __shared__ float Bs[32][65];
    const int tid = threadIdx.x;
    const int bm = blockIdx.y * 64, bn = blockIdx.x * 64;
    const int tx = tid & 15, ty = tid >> 4;

    float acc[4][4];
    #pragma unroll
    for (int i = 0; i < 4; ++i)
        #pragma unroll
        for (int j = 0; j < 4; ++j) acc[i][j] = 0.f;

    for (int k0 = 0; k0 < K; k0 += 32) {
        #pragma unroll
        for (int i = 0; i < 8; ++i) {
            int lin = tid + i * 256;             // 0..2047
            int r = lin >> 5, c = lin & 31;
            As[r][c] = A[(size_t)(bm + r) * K + k0 + c];
        }
        #pragma unroll
        for (int i = 0; i < 8; ++i) {
            int lin = tid + i * 256;
            int o = lin >> 5, kk = lin & 31;
            Bs[kk][o] = Bw[(size_t)(bn + o) * K + k0 + kk];
        }
        __syncthreads();
        #pragma unroll
        for (int kk = 0; kk < 32; ++kk) {
            float av[4], bv[4];
            #pragma unroll
            for (int i = 0; i < 4; ++i) av[i] = As[ty * 4 + i][kk];
            #pragma unroll
            for (int j = 0; j < 4; ++j) bv[j] = Bs[kk][tx * 4 + j];
            #pragma unroll
            for (int i = 0; i < 4; ++i)
                #pragma unroll
                for (int j = 0; j < 4; ++j)
                    acc[i][j] = fmaf(av[i], bv[j], acc[i][j]);
        }
        __syncthreads();
    }
    #pragma unroll
    for (int i = 0; i < 4; ++i) {
        #pragma unroll
        for (int j = 0; j < 4; ++j) {
            int o = bn + tx * 4 + j;
            float v = acc[i][j] + bias[o];
            if (RELU) v = v > 0.f ? v : 0.f;
            C[(size_t)(bm + ty * 4 + i) * N + o] = v;
        }
    }
}

extern "C" void kernel_launch(void* const* d_in, const int* in_sizes, int n_in,
                              void* d_out, int out_size, void* d_ws, size_t ws_size,
                              hipStream_t stream) {
    // Input order: dict order from setup_inputs. Disambiguate vs signature
    // order defensively via in_sizes[3] (w2=24576 in dict order, g1=64 in sig order).
    int I_x, I_w1, I_b1, I_w2, I_b2, I_w3, I_b3;
    int I_g1, I_be1, I_m1, I_v1, I_g2, I_be2, I_m2, I_v2, I_g3, I_be3, I_m3, I_v3;
    int I_lw1, I_lb1, I_lw2, I_lb2;
    if (in_sizes[3] == 24576) {
        // dict order: x,w1,b1,w2,b2,w3,b3,g1,be1,m1,v1,g2,be2,m2,v2,g3,be3,m3,v3,lw1,lb1,lw2,lb2
        I_x=0; I_w1=1; I_b1=2; I_w2=3; I_b2=4; I_w3=5; I_b3=6;
        I_g1=7; I_be1=8; I_m1=9; I_v1=10; I_g2=11; I_be2=12; I_m2=13; I_v2=14;
        I_g3=15; I_be3=16; I_m3=17; I_v3=18; I_lw1=19; I_lb1=20; I_lw2=21; I_lb2=22;
    } else {
        // signature order: x,w1,b1,g1,be1,m1,v1,w2,b2,g2,be2,m2,v2,w3,b3,g3,be3,m3,v3,lw1,lb1,lw2,lb2
        I_x=0; I_w1=1; I_b1=2; I_g1=3; I_be1=4; I_m1=5; I_v1=6;
        I_w2=7; I_b2=8; I_g2=9; I_be2=10; I_m2=11; I_v2=12;
        I_w3=13; I_b3=14; I_g3=15; I_be3=16; I_m3=17; I_v3=18;
        I_lw1=19; I_lb1=20; I_lw2=21; I_lb2=22;
    }

    const float* x   = (const float*)d_in[I_x];
    const float* w1  = (const float*)d_in[I_w1];
    const float* b1  = (const float*)d_in[I_b1];
    const float* w2  = (const float*)d_in[I_w2];
    const float* b2  = (const float*)d_in[I_b2];
    const float* w3  = (const float*)d_in[I_w3];
    const float* b3  = (const float*)d_in[I_b3];
    const float* g1  = (const float*)d_in[I_g1];
    const float* be1 = (const float*)d_in[I_be1];
    const float* m1  = (const float*)d_in[I_m1];
    const float* v1  = (const float*)d_in[I_v1];
    const float* g2  = (const float*)d_in[I_g2];
    const float* be2 = (const float*)d_in[I_be2];
    const float* m2  = (const float*)d_in[I_m2];
    const float* v2  = (const float*)d_in[I_v2];
    const float* g3  = (const float*)d_in[I_g3];
    const float* be3 = (const float*)d_in[I_be3];
    const float* m3  = (const float*)d_in[I_m3];
    const float* v3  = (const float*)d_in[I_v3];
    const float* lw1 = (const float*)d_in[I_lw1];
    const float* lb1 = (const float*)d_in[I_lb1];
    const float* lw2 = (const float*)d_in[I_lw2];
    const float* lb2 = (const float*)d_in[I_lb2];

    const int Nseq = 1024;   // B*S = 16*64
    float* ms    = (float*)d_ws;                          // [1024][3328]
    float* h2lin = ms + (size_t)Nseq * 3328;              // [1024][512]
    float* out   = (float*)d_out;                         // [1024][256]

    conv_fused_kernel<<<Nseq, 256, 0, stream>>>(
        x, w1, b1, w2, b2, w3, b3,
        g1, be1, m1, v1, g2, be2, m2, v2, g3, be3, m3, v3, ms);

    {
        dim3 grid(512 / 64, Nseq / 64);
        gemm_bt_kernel<true><<<grid, 256, 0, stream>>>(ms, lw1, lb1, h2lin, Nseq, 512, 3328);
    }
    {
        dim3 grid(256 / 64, Nseq / 64);
        gemm_bt_kernel<false><<<grid, 256, 0, stream>>>(h2lin, lw2, lb2, out, Nseq, 256, 512);
    }
}

// Round 2
// 235.549 us; speedup vs baseline: 2.8317x; 2.8317x over previous
//
#include <hip/hip_runtime.h>
#include <hip/hip_bf16.h>

typedef __attribute__((ext_vector_type(8))) short short8v;
typedef __attribute__((ext_vector_type(4))) short short4v;
typedef __attribute__((ext_vector_type(4))) float f32x4;

#define LRELU(v) ((v) > 0.f ? (v) : 0.1f * (v))
#define MFMA16(a, b, c) __builtin_amdgcn_mfma_f32_16x16x32_bf16((a), (b), (c), 0, 0, 0)

__device__ inline unsigned short f2bf(float f) {
    unsigned u = __float_as_uint(f);
    u += 0x7FFF + ((u >> 16) & 1);          // RNE
    return (unsigned short)(u >> 16);
}
__device__ inline float bf2f(unsigned short h) {
    return __uint_as_float(((unsigned)h) << 16);
}

// ---------------------------------------------------------------------------
// Prep: split weights into bf16 hi+lo planes; repack conv weights.
//  Wp2[co][k*64+ci]  (row-major, K-ordering (k,ci))          : 128*192
//  Wq3 fragment-packed: ((ctile*12+kf)*64+lane)*8+i  where
//     co = ctile*16+(lane&15), Kidx = kf*32+(lane>>4)*8+i, k=Kidx>>7, ci=Kidx&127
//  lw1/lw2: straight bf16 cast [N][K]
// ---------------------------------------------------------------------------
__global__ __launch_bounds__(256) void prep_weights(
    const float* __restrict__ w2, const float* __restrict__ w3,
    const float* __restrict__ lw1, const float* __restrict__ lw2,
    short* __restrict__ Wp2h, short* __restrict__ Wp2l,
    short* __restrict__ Wq3h, short* __restrict__ Wq3l,
    short* __restrict__ lw1h, short* __restrict__ lw1l,
    short* __restrict__ lw2h, short* __restrict__ lw2l)
{
    const int N1 = 24576, N2 = 98304, N3 = 1703936, N4 = 131072;
    const int total = N1 + N2 + N3 + N4;
    for (int i = blockIdx.x * 256 + threadIdx.x; i < total; i += gridDim.x * 256) {
        float v; short *ph, *pl; int o;
        if (i < N1) {
            o = i;
            int co = i / 192, r = i - co * 192, k = r >> 6, ci = r & 63;
            v = w2[(co * 64 + ci) * 3 + k];
            ph = Wp2h; pl = Wp2l;
        } else if (i < N1 + N2) {
            o = i - N1;
            int ii = o & 7, q = o >> 3;
            int lane = q & 63, q2 = q >> 6;
            int kf = q2 % 12, ctile = q2 / 12;
            int co = ctile * 16 + (lane & 15);
            int Kidx = kf * 32 + (lane >> 4) * 8 + ii;
            v = w3[(co * 128 + (Kidx & 127)) * 3 + (Kidx >> 7)];
            ph = Wq3h; pl = Wq3l;
        } else if (i < N1 + N2 + N3) {
            o = i - N1 - N2;
            v = lw1[o]; ph = lw1h; pl = lw1l;
        } else {
            o = i - N1 - N2 - N3;
            v = lw2[o]; ph = lw2h; pl = lw2l;
        }
        unsigned short h = f2bf(v);
        float resid = v - bf2f(h);
        ph[o] = (short)h;
        pl[o] = (short)f2bf(resid);
    }
}

// ---------------------------------------------------------------------------
// Fused conv1(VALU fp32) + conv2/conv3 (bf16 MFMA, split weights) + pools.
// One workgroup (4 waves) per sequence. h1/h2 bf16 time-major, XOR-swizzled.
// ---------------------------------------------------------------------------
__global__ __launch_bounds__(256) void conv_fused_mfma(
    const float* __restrict__ xg, const float* __restrict__ w1,
    const float* __restrict__ b1, const float* __restrict__ g1, const float* __restrict__ be1,
    const float* __restrict__ m1, const float* __restrict__ v1,
    const float* __restrict__ b2, const float* __restrict__ g2, const float* __restrict__ be2,
    const float* __restrict__ m2, const float* __restrict__ v2,
    const float* __restrict__ b3, const float* __restrict__ g3, const float* __restrict__ be3,
    const float* __restrict__ m3, const float* __restrict__ v3,
    const short* __restrict__ Wp2h, const short* __restrict__ Wp2l,
    const short* __restrict__ Wq3h, const short* __restrict__ Wq3l,
    short* __restrict__ ms)
{
    __shared__ float sx[6][132];                    // col t+1 holds time t
    __shared__ __align__(16) short h1s[130 * 64];   // [row=t+1][ci], swizzled
    __shared__ __align__(16) short h2s[130 * 128];  // [row=t+1][ci], swizzled
    __shared__ float A1c[64], C1c[64], A2c[128], C2c[128], A3c[256], C3c[256];

    const int tid = threadIdx.x;
    const int n = blockIdx.x;
    const int wv = tid >> 6, lane = tid & 63;
    const int l15 = lane & 15, lhi = lane >> 4;

    // BN fold: y = A*conv + C
    if (tid < 64)  { float a = g1[tid] * rsqrtf(v1[tid] + 1e-5f); A1c[tid] = a; C1c[tid] = (b1[tid] - m1[tid]) * a + be1[tid]; }
    if (tid < 128) { float a = g2[tid] * rsqrtf(v2[tid] + 1e-5f); A2c[tid] = a; C2c[tid] = (b2[tid] - m2[tid]) * a + be2[tid]; }
    { float a = g3[tid] * rsqrtf(v3[tid] + 1e-5f); A3c[tid] = a; C3c[tid] = (b3[tid] - m3[tid]) * a + be3[tid]; }

    const float* xrow = xg + (size_t)n * (128 * 6);
    #pragma unroll
    for (int i = 0; i < 3; ++i) {
        int idx = tid + i * 256;
        float vv = xrow[idx];
        int t = idx / 6, c = idx - t * 6;
        sx[c][t + 1] = vv;
    }
    if (tid < 6)   { sx[tid][0] = 0.f; sx[tid][129] = 0.f; }
    if (tid < 64)  { h1s[tid] = 0; h1s[129 * 64 + tid] = 0; }    // halo rows
    if (tid < 128) { h2s[tid] = 0; h2s[129 * 128 + tid] = 0; }
    __syncthreads();

    // ---- conv1: 6 -> 64, fp32 VALU; thread = 8co x 4t ----
    {
        const int cIdx = tid >> 5, tIdx = tid & 31;
        const int co0 = cIdx * 8, t0 = tIdx * 4;
        float acc[8][4];
        #pragma unroll
        for (int c = 0; c < 8; ++c)
            #pragma unroll
            for (int t = 0; t < 4; ++t) acc[c][t] = 0.f;
        #pragma unroll
        for (int ci = 0; ci < 6; ++ci) {
            float s[6];
            #pragma unroll
            for (int u = 0; u < 6; ++u) s[u] = sx[ci][t0 + u];
            #pragma unroll
            for (int c = 0; c < 8; ++c) {
                const float* wp = w1 + ((co0 + c) * 6 + ci) * 3;
                float wa = wp[0], wb = wp[1], wc = wp[2];
                #pragma unroll
                for (int t = 0; t < 4; ++t)
                    acc[c][t] = fmaf(wa, s[t], fmaf(wb, s[t + 1], fmaf(wc, s[t + 2], acc[c][t])));
            }
        }
        char* h1b = (char*)h1s;
        #pragma unroll
        for (int t = 0; t < 4; ++t) {
            short8v pk;
            #pragma unroll
            for (int c = 0; c < 8; ++c) {
                float v = fmaf(A1c[co0 + c], acc[c][t], C1c[co0 + c]);
                v = LRELU(v);
                pk[c] = (short)f2bf(v);
            }
            int row = t0 + t + 1;
            int byt = (row * 128 + cIdx * 16) ^ ((row & 7) << 4);
            *(short8v*)(h1b + byt) = pk;
        }
    }
    __syncthreads();

    // ---- conv2: 64 -> 128 MFMA (A=weights: D row=co, col=t) ----
    {
        const int co0w = wv * 32;
        f32x4 acc[2][8];
        #pragma unroll
        for (int mi = 0; mi < 2; ++mi)
            #pragma unroll
            for (int tt = 0; tt < 8; ++tt) acc[mi][tt] = (f32x4){0.f, 0.f, 0.f, 0.f};
        const char* h1b = (const char*)h1s;
        for (int kf = 0; kf < 6; ++kf) {
            int k = kf >> 1, ci0 = (kf & 1) * 32;
            int col2 = (ci0 + lhi * 8) * 2;
            short8v bfr[8];
            #pragma unroll
            for (int tt = 0; tt < 8; ++tt) {
                int row = tt * 16 + l15 + k;
                int byt = (row * 128 + col2) ^ ((row & 7) << 4);
                bfr[tt] = *(const short8v*)(h1b + byt);
            }
            #pragma unroll
            for (int mi = 0; mi < 2; ++mi) {
                int woff = (co0w + mi * 16 + l15) * 192 + kf * 32 + lhi * 8;
                short8v ah = *(const short8v*)(Wp2h + woff);
                short8v al = *(const short8v*)(Wp2l + woff);
                #pragma unroll
                for (int tt = 0; tt < 8; ++tt) {
                    acc[mi][tt] = MFMA16(ah, bfr[tt], acc[mi][tt]);
                    acc[mi][tt] = MFMA16(al, bfr[tt], acc[mi][tt]);
                }
            }
        }
        char* h2b = (char*)h2s;
        #pragma unroll
        for (int mi = 0; mi < 2; ++mi) {
            int cob = co0w + mi * 16 + lhi * 4;
            float a0 = A2c[cob + 0], a1 = A2c[cob + 1], a2 = A2c[cob + 2], a3 = A2c[cob + 3];
            float c0 = C2c[cob + 0], c1 = C2c[cob + 1], c2 = C2c[cob + 2], c3 = C2c[cob + 3];
            #pragma unroll
            for (int tt = 0; tt < 8; ++tt) {
                int t = tt * 16 + l15;
                float v0 = fmaf(a0, acc[mi][tt][0], c0); v0 = LRELU(v0);
                float v1_ = fmaf(a1, acc[mi][tt][1], c1); v1_ = LRELU(v1_);
                float v2_ = fmaf(a2, acc[mi][tt][2], c2); v2_ = LRELU(v2_);
                float v3_ = fmaf(a3, acc[mi][tt][3], c3); v3_ = LRELU(v3_);
                short4v pk;
                pk[0] = (short)f2bf(v0); pk[1] = (short)f2bf(v1_);
                pk[2] = (short)f2bf(v2_); pk[3] = (short)f2bf(v3_);
                int row = t + 1;
                int byt = (row * 256 + cob * 2) ^ ((row & 7) << 4);
                *(short4v*)(h2b + byt) = pk;
            }
        }
    }
    __syncthreads();

    // ---- conv3: 128 -> 256 MFMA, swapped (A=acts: D row=t, col=co) + pools ----
    {
        const int cobw = wv * 64;
        short* msrow = ms + (size_t)n * 3328;
        const char* h2b = (const char*)h2s;
        #pragma unroll 1
        for (int cp = 0; cp < 2; ++cp) {
            f32x4 acc[2][8];
            #pragma unroll
            for (int c2 = 0; c2 < 2; ++c2)
                #pragma unroll
                for (int tt = 0; tt < 8; ++tt) acc[c2][tt] = (f32x4){0.f, 0.f, 0.f, 0.f};
            for (int kf = 0; kf < 12; ++kf) {
                int k = kf >> 2, ci0 = (kf & 3) * 32;
                int col2 = (ci0 + lhi * 8) * 2;
                short8v afr[8];
                #pragma unroll
                for (int tt = 0; tt < 8; ++tt) {
                    int row = tt * 16 + l15 + k;
                    int byt = (row * 256 + col2) ^ ((row & 7) << 4);
                    afr[tt] = *(const short8v*)(h2b + byt);
                }
                #pragma unroll
                for (int c2 = 0; c2 < 2; ++c2) {
                    int ctg = wv * 4 + cp * 2 + c2;
                    size_t foff = ((size_t)(ctg * 12 + kf) * 64 + lane) * 8;
                    short8v bh = *(const short8v*)(Wq3h + foff);
                    short8v bl = *(const short8v*)(Wq3l + foff);
                    #pragma unroll
                    for (int tt = 0; tt < 8; ++tt) {
                        acc[c2][tt] = MFMA16(afr[tt], bh, acc[c2][tt]);
                        acc[c2][tt] = MFMA16(afr[tt], bl, acc[c2][tt]);
                    }
                }
            }
            #pragma unroll
            for (int c2 = 0; c2 < 2; ++c2) {
                int co = cobw + (cp * 2 + c2) * 16 + l15;
                float a3v = A3c[co], c3v = C3c[co];
                float s16[8];
                #pragma unroll
                for (int tt = 0; tt < 8; ++tt) {
                    float s = 0.f;
                    #pragma unroll
                    for (int r = 0; r < 4; ++r) {
                        float v = fmaf(a3v, acc[c2][tt][r], c3v);
                        v = LRELU(v);
                        s += v;
                    }
                    s += __shfl_xor(s, 16);
                    s += __shfl_xor(s, 32);
                    s16[tt] = s;
                }
                if (lane < 16) {
                    #pragma unroll
                    for (int tt = 0; tt < 8; ++tt)
                        msrow[co * 8 + tt] = (short)f2bf(s16[tt] * (1.f / 16.f));
                    float g = 0.f;
                    #pragma unroll
                    for (int j = 0; j < 4; ++j) {
                        float s32 = s16[2 * j] + s16[2 * j + 1];
                        msrow[2048 + co * 4 + j] = (short)f2bf(s32 * (1.f / 32.f));
                        g += s32;
                    }
                    msrow[3072 + co] = (short)f2bf(g * (1.f / 128.f));
                }
            }
        }
    }
}

// ---------------------------------------------------------------------------
// C[M][N] = act(Act[M][K] x W[N][K]^T + bias), W split hi/lo bf16.
// LDS-free: both operands direct 16B loads (L2). Wave tile 32n x 32m.
// ---------------------------------------------------------------------------
template <int K, bool RELU, bool OUTF32>
__global__ __launch_bounds__(256) void gemm_wsplit(
    const short* __restrict__ Wh, const short* __restrict__ Wl,
    const short* __restrict__ Act, const float* __restrict__ bias,
    void* __restrict__ Cout, int Ntot)
{
    const int tid = threadIdx.x;
    const int w = tid >> 6, lane = tid & 63;
    const int l15 = lane & 15, lhi = lane >> 4;
    const int n0 = blockIdx.x * 64 + (w & 1) * 32;
    const int m0 = blockIdx.y * 64 + (w >> 1) * 32;

    f32x4 acc[2][2];
    #pragma unroll
    for (int i = 0; i < 2; ++i)
        #pragma unroll
        for (int j = 0; j < 2; ++j) acc[i][j] = (f32x4){0.f, 0.f, 0.f, 0.f};

    const short* aw0 = Wh + (size_t)(n0 + l15) * K + lhi * 8;
    const short* aw1 = aw0 + 16 * K;
    const short* av0 = Wl + (size_t)(n0 + l15) * K + lhi * 8;
    const short* av1 = av0 + 16 * K;
    const short* bp0 = Act + (size_t)(m0 + l15) * K + lhi * 8;
    const short* bp1 = bp0 + 16 * K;

    #pragma unroll 4
    for (int k0 = 0; k0 < K; k0 += 32) {
        short8v b0 = *(const short8v*)(bp0 + k0);
        short8v b1 = *(const short8v*)(bp1 + k0);
        short8v a0h = *(const short8v*)(aw0 + k0);
        short8v a1h = *(const short8v*)(aw1 + k0);
        short8v a0l = *(const short8v*)(av0 + k0);
        short8v a1l = *(const short8v*)(av1 + k0);
        acc[0][0] = MFMA16(a0h, b0, acc[0][0]); acc[0][0] = MFMA16(a0l, b0, acc[0][0]);
        acc[0][1] = MFMA16(a0h, b1, acc[0][1]); acc[0][1] = MFMA16(a0l, b1, acc[0][1]);
        acc[1][0] = MFMA16(a1h, b0, acc[1][0]); acc[1][0] = MFMA16(a1l, b0, acc[1][0]);
        acc[1][1] = MFMA16(a1h, b1, acc[1][1]); acc[1][1] = MFMA16(a1l, b1, acc[1][1]);
    }

    #pragma unroll
    for (int ni = 0; ni < 2; ++ni) {
        int nb = n0 + ni * 16 + lhi * 4;
        f32x4 bs = *(const f32x4*)(bias + nb);
        #pragma unroll
        for (int mi = 0; mi < 2; ++mi) {
            int m = m0 + mi * 16 + l15;
            f32x4 vv;
            #pragma unroll
            for (int r = 0; r < 4; ++r) {
                float v = acc[ni][mi][r] + bs[r];
                if (RELU) v = v > 0.f ? v : 0.f;
                vv[r] = v;
            }
            if (OUTF32) {
                *(f32x4*)((float*)Cout + (size_t)m * Ntot + nb) = vv;
            } else {
                short4v pk;
                #pragma unroll
                for (int r = 0; r < 4; ++r) pk[r] = (short)f2bf(vv[r]);
                *(short4v*)((short*)Cout + (size_t)m * Ntot + nb) = pk;
            }
        }
    }
}

extern "C" void kernel_launch(void* const* d_in, const int* in_sizes, int n_in,
                              void* d_out, int out_size, void* d_ws, size_t ws_size,
                              hipStream_t stream) {
    int I_x, I_w1, I_b1, I_w2, I_b2, I_w3, I_b3;
    int I_g1, I_be1, I_m1, I_v1, I_g2, I_be2, I_m2, I_v2, I_g3, I_be3, I_m3, I_v3;
    int I_lw1, I_lb1, I_lw2, I_lb2;
    if (in_sizes[3] == 24576) {
        I_x=0; I_w1=1; I_b1=2; I_w2=3; I_b2=4; I_w3=5; I_b3=6;
        I_g1=7; I_be1=8; I_m1=9; I_v1=10; I_g2=11; I_be2=12; I_m2=13; I_v2=14;
        I_g3=15; I_be3=16; I_m3=17; I_v3=18; I_lw1=19; I_lb1=20; I_lw2=21; I_lb2=22;
    } else {
        I_x=0; I_w1=1; I_b1=2; I_g1=3; I_be1=4; I_m1=5; I_v1=6;
        I_w2=7; I_b2=8; I_g2=9; I_be2=10; I_m2=11; I_v2=12;
        I_w3=13; I_b3=14; I_g3=15; I_be3=16; I_m3=17; I_v3=18;
        I_lw1=19; I_lb1=20; I_lw2=21; I_lb2=22;
    }

    const float* x   = (const float*)d_in[I_x];
    const float* w1  = (const float*)d_in[I_w1];
    const float* b1  = (const float*)d_in[I_b1];
    const float* w2  = (const float*)d_in[I_w2];
    const float* b2  = (const float*)d_in[I_b2];
    const float* w3  = (const float*)d_in[I_w3];
    const float* b3  = (const float*)d_in[I_b3];
    const float* g1  = (const float*)d_in[I_g1];
    const float* be1 = (const float*)d_in[I_be1];
    const float* m1  = (const float*)d_in[I_m1];
    const float* v1  = (const float*)d_in[I_v1];
    const float* g2  = (const float*)d_in[I_g2];
    const float* be2 = (const float*)d_in[I_be2];
    const float* m2  = (const float*)d_in[I_m2];
    const float* v2  = (const float*)d_in[I_v2];
    const float* g3  = (const float*)d_in[I_g3];
    const float* be3 = (const float*)d_in[I_be3];
    const float* m3  = (const float*)d_in[I_m3];
    const float* v3  = (const float*)d_in[I_v3];
    const float* lw1 = (const float*)d_in[I_lw1];
    const float* lb1 = (const float*)d_in[I_lb1];
    const float* lw2 = (const float*)d_in[I_lw2];
    const float* lb2 = (const float*)d_in[I_lb2];

    char* wsb = (char*)d_ws;
    short* ms   = (short*)(wsb);                 // 1024*3328 bf16 = 6,815,744 B
    short* h2l  = (short*)(wsb + 6815744);       // 1024*512  bf16 = 1,048,576 B
    short* Wp2h = (short*)(wsb + 7864320);       // 24576*2
    short* Wp2l = (short*)(wsb + 7913472);
    short* Wq3h = (short*)(wsb + 7962624);       // 98304*2
    short* Wq3l = (short*)(wsb + 8159232);
    short* lw1h = (short*)(wsb + 8355840);       // 1703936*2
    short* lw1l = (short*)(wsb + 11763712);
    short* lw2h = (short*)(wsb + 15171584);      // 131072*2
    short* lw2l = (short*)(wsb + 15433728);      // end 15,695,872 B

    prep_weights<<<2048, 256, 0, stream>>>(w2, w3, lw1, lw2,
        Wp2h, Wp2l, Wq3h, Wq3l, lw1h, lw1l, lw2h, lw2l);

    conv_fused_mfma<<<1024, 256, 0, stream>>>(
        x, w1, b1, g1, be1, m1, v1, b2, g2, be2, m2, v2,
        b3, g3, be3, m3, v3, Wp2h, Wp2l, Wq3h, Wq3l, ms);

    gemm_wsplit<3328, true, false><<<dim3(8, 16), 256, 0, stream>>>(
        lw1h, lw1l, ms, lb1, h2l, 512);
    gemm_wsplit<512, false, true><<<dim3(4, 16), 256, 0, stream>>>(
        lw2h, lw2l, h2l, lb2, d_out, 256);
}

// Round 3
// 122.520 us; speedup vs baseline: 5.4441x; 1.9225x over previous
//
#include <hip/hip_runtime.h>
#include <hip/hip_bf16.h>

typedef __attribute__((ext_vector_type(8))) short short8v;
typedef __attribute__((ext_vector_type(4))) short short4v;
typedef __attribute__((ext_vector_type(4))) float f32x4;

#define LRELU(v) ((v) > 0.f ? (v) : 0.1f * (v))
#define MFMA16(a, b, c) __builtin_amdgcn_mfma_f32_16x16x32_bf16((a), (b), (c), 0, 0, 0)

__device__ inline unsigned short f2bf(float f) {
    unsigned u = __float_as_uint(f);
    u += 0x7FFF + ((u >> 16) & 1);          // RNE
    return (unsigned short)(u >> 16);
}
__device__ inline float bf2f(unsigned short h) {
    return __uint_as_float(((unsigned)h) << 16);
}

// ---------------------------------------------------------------------------
// Prep: split weights into bf16 hi+lo planes.
//  Wf2 fragment-packed: ((ctile*6+kf)*64+lane)*8+i ; co=ctile*16+(lane&15),
//     Kidx=kf*32+(lane>>4)*8+i, k=Kidx>>6, ci=Kidx&63   (ctile 0..7)
//  Wq3 fragment-packed: ((ctile*12+kf)*64+lane)*8+i ; co=ctile*16+(lane&15),
//     Kidx=kf*32+(lane>>4)*8+i, k=Kidx>>7, ci=Kidx&127  (ctile 0..15)
//  lw1/lw2: straight bf16 cast [N][K]
// ---------------------------------------------------------------------------
__global__ __launch_bounds__(256) void prep_weights(
    const float* __restrict__ w2, const float* __restrict__ w3,
    const float* __restrict__ lw1, const float* __restrict__ lw2,
    short* __restrict__ Wf2h, short* __restrict__ Wf2l,
    short* __restrict__ Wq3h, short* __restrict__ Wq3l,
    short* __restrict__ lw1h, short* __restrict__ lw1l,
    short* __restrict__ lw2h, short* __restrict__ lw2l)
{
    const int N1 = 24576, N2 = 98304, N3 = 1703936, N4 = 131072;
    const int total = N1 + N2 + N3 + N4;
    for (int i = blockIdx.x * 256 + threadIdx.x; i < total; i += gridDim.x * 256) {
        float v; short *ph, *pl; int o;
        if (i < N1) {
            o = i;
            int ii = o & 7, q = o >> 3;
            int lane = q & 63, q2 = q >> 6;
            int kf = q2 % 6, ctile = q2 / 6;
            int co = ctile * 16 + (lane & 15);
            int Kidx = kf * 32 + (lane >> 4) * 8 + ii;
            v = w2[(co * 64 + (Kidx & 63)) * 3 + (Kidx >> 6)];
            ph = Wf2h; pl = Wf2l;
        } else if (i < N1 + N2) {
            o = i - N1;
            int ii = o & 7, q = o >> 3;
            int lane = q & 63, q2 = q >> 6;
            int kf = q2 % 12, ctile = q2 / 12;
            int co = ctile * 16 + (lane & 15);
            int Kidx = kf * 32 + (lane >> 4) * 8 + ii;
            v = w3[(co * 128 + (Kidx & 127)) * 3 + (Kidx >> 7)];
            ph = Wq3h; pl = Wq3l;
        } else if (i < N1 + N2 + N3) {
            o = i - N1 - N2;
            v = lw1[o]; ph = lw1h; pl = lw1l;
        } else {
            o = i - N1 - N2 - N3;
            v = lw2[o]; ph = lw2h; pl = lw2l;
        }
        unsigned short h = f2bf(v);
        float resid = v - bf2f(h);
        ph[o] = (short)h;
        pl[o] = (short)f2bf(resid);
    }
}

// ---------------------------------------------------------------------------
// Fused conv1(VALU fp32) + conv2/conv3 (bf16 MFMA, split weights) + pools.
// 512 threads / 8 waves per block, one block per sequence.
// Wave split: wv_t = wv&1 (time half), wv_c = wv>>1 (channel group).
// ---------------------------------------------------------------------------
__global__ __launch_bounds__(512, 4) void conv_fused_mfma(
    const float* __restrict__ xg, const float* __restrict__ w1,
    const float* __restrict__ b1, const float* __restrict__ g1, const float* __restrict__ be1,
    const float* __restrict__ m1, const float* __restrict__ v1,
    const float* __restrict__ b2, const float* __restrict__ g2, const float* __restrict__ be2,
    const float* __restrict__ m2, const float* __restrict__ v2,
    const float* __restrict__ b3, const float* __restrict__ g3, const float* __restrict__ be3,
    const float* __restrict__ m3, const float* __restrict__ v3,
    const short* __restrict__ Wf2h, const short* __restrict__ Wf2l,
    const short* __restrict__ Wq3h, const short* __restrict__ Wq3l,
    short* __restrict__ ms)
{
    __shared__ float sx[6][132];                    // col t+1 holds time t
    __shared__ __align__(16) short h1s[130 * 64];   // [row=t+1][ci], swizzled
    __shared__ __align__(16) short h2s[130 * 128];  // [row=t+1][ci], swizzled
    __shared__ float A1c[64], C1c[64], A2c[128], C2c[128], A3c[256], C3c[256];
    __shared__ float gsum[512];                     // [wv_t][co]

    const int tid = threadIdx.x;
    const int n = blockIdx.x;
    const int wv = tid >> 6, lane = tid & 63;
    const int l15 = lane & 15, lhi = lane >> 4;
    const int wv_t = wv & 1, wv_c = wv >> 1;
    const int tb = wv_t * 4;                        // 16-t tile base for this wave

    // BN fold: y = A*conv + C
    if (tid < 64)  { float a = g1[tid] * rsqrtf(v1[tid] + 1e-5f); A1c[tid] = a; C1c[tid] = (b1[tid] - m1[tid]) * a + be1[tid]; }
    if (tid < 128) { float a = g2[tid] * rsqrtf(v2[tid] + 1e-5f); A2c[tid] = a; C2c[tid] = (b2[tid] - m2[tid]) * a + be2[tid]; }
    if (tid < 256) { float a = g3[tid] * rsqrtf(v3[tid] + 1e-5f); A3c[tid] = a; C3c[tid] = (b3[tid] - m3[tid]) * a + be3[tid]; }

    const float* xrow = xg + (size_t)n * 768;
    {
        int idx = tid;
        float vv = xrow[idx];
        int t = idx / 6, c = idx - t * 6;
        sx[c][t + 1] = vv;
        idx = tid + 512;
        if (idx < 768) {
            vv = xrow[idx];
            t = idx / 6; c = idx - t * 6;
            sx[c][t + 1] = vv;
        }
    }
    if (tid < 6)   { sx[tid][0] = 0.f; sx[tid][129] = 0.f; }
    if (tid < 64)  { h1s[tid] = 0; h1s[129 * 64 + tid] = 0; }
    if (tid < 128) { h2s[tid] = 0; h2s[129 * 128 + tid] = 0; }
    __syncthreads();

    // ---- conv1: 6 -> 64, fp32 VALU; thread = 4co x 4t (co across lanes) ----
    {
        const int t0 = (tid >> 4) * 4, co0 = (tid & 15) * 4;
        float acc[4][4];
        #pragma unroll
        for (int c = 0; c < 4; ++c)
            #pragma unroll
            for (int t = 0; t < 4; ++t) acc[c][t] = 0.f;
        #pragma unroll
        for (int ci = 0; ci < 6; ++ci) {
            float s[6];
            #pragma unroll
            for (int u = 0; u < 6; ++u) s[u] = sx[ci][t0 + u];
            #pragma unroll
            for (int c = 0; c < 4; ++c) {
                const float* wp = w1 + ((co0 + c) * 6 + ci) * 3;
                float wa = wp[0], wb = wp[1], wc = wp[2];
                #pragma unroll
                for (int t = 0; t < 4; ++t)
                    acc[c][t] = fmaf(wa, s[t], fmaf(wb, s[t + 1], fmaf(wc, s[t + 2], acc[c][t])));
            }
        }
        char* h1b = (char*)h1s;
        #pragma unroll
        for (int t = 0; t < 4; ++t) {
            short4v pk;
            #pragma unroll
            for (int c = 0; c < 4; ++c) {
                float v = fmaf(A1c[co0 + c], acc[c][t], C1c[co0 + c]);
                v = LRELU(v);
                pk[c] = (short)f2bf(v);
            }
            int row = t0 + t + 1;
            int byt = (row * 128 + co0 * 2) ^ ((row & 7) << 4);
            *(short4v*)(h1b + byt) = pk;
        }
    }
    __syncthreads();

    // ---- conv2: 64 -> 128 MFMA (A=weights: D row=co, col=t) ----
    {
        f32x4 acc[2][4];
        #pragma unroll
        for (int mi = 0; mi < 2; ++mi)
            #pragma unroll
            for (int j = 0; j < 4; ++j) acc[mi][j] = (f32x4){0.f, 0.f, 0.f, 0.f};
        const char* h1b = (const char*)h1s;
        for (int kf = 0; kf < 6; ++kf) {
            int k = kf >> 1, ci0 = (kf & 1) * 32;
            int colb = (ci0 + lhi * 8) * 2;
            short8v bfr[4];
            #pragma unroll
            for (int j = 0; j < 4; ++j) {
                int row = (tb + j) * 16 + l15 + k;
                bfr[j] = *(const short8v*)(h1b + ((row * 128 + colb) ^ ((row & 7) << 4)));
            }
            #pragma unroll
            for (int mi = 0; mi < 2; ++mi) {
                size_t woff = ((size_t)((wv_c * 2 + mi) * 6 + kf) * 64 + lane) * 8;
                short8v ah = *(const short8v*)(Wf2h + woff);
                short8v al = *(const short8v*)(Wf2l + woff);
                #pragma unroll
                for (int j = 0; j < 4; ++j) {
                    acc[mi][j] = MFMA16(ah, bfr[j], acc[mi][j]);
                    acc[mi][j] = MFMA16(al, bfr[j], acc[mi][j]);
                }
            }
        }
        char* h2b = (char*)h2s;
        #pragma unroll
        for (int mi = 0; mi < 2; ++mi) {
            int cob = (wv_c * 2 + mi) * 16 + lhi * 4;
            float a0 = A2c[cob + 0], a1 = A2c[cob + 1], a2 = A2c[cob + 2], a3 = A2c[cob + 3];
            float c0 = C2c[cob + 0], c1 = C2c[cob + 1], c2 = C2c[cob + 2], c3 = C2c[cob + 3];
            #pragma unroll
            for (int j = 0; j < 4; ++j) {
                int t = (tb + j) * 16 + l15;
                float v0 = fmaf(a0, acc[mi][j][0], c0); v0 = LRELU(v0);
                float v1_ = fmaf(a1, acc[mi][j][1], c1); v1_ = LRELU(v1_);
                float v2_ = fmaf(a2, acc[mi][j][2], c2); v2_ = LRELU(v2_);
                float v3_ = fmaf(a3, acc[mi][j][3], c3); v3_ = LRELU(v3_);
                short4v pk;
                pk[0] = (short)f2bf(v0); pk[1] = (short)f2bf(v1_);
                pk[2] = (short)f2bf(v2_); pk[3] = (short)f2bf(v3_);
                int row = t + 1;
                int byt = (row * 256 + cob * 2) ^ ((row & 7) << 4);
                *(short4v*)(h2b + byt) = pk;
            }
        }
    }
    __syncthreads();

    // ---- conv3: 128 -> 256 MFMA swapped (A=acts: D row=t, col=co) + pools ----
    {
        f32x4 acc[4][4];            // [c4][j]
        #pragma unroll
        for (int c4 = 0; c4 < 4; ++c4)
            #pragma unroll
            for (int j = 0; j < 4; ++j) acc[c4][j] = (f32x4){0.f, 0.f, 0.f, 0.f};
        const char* h2b = (const char*)h2s;
        for (int kf = 0; kf < 12; ++kf) {
            int k = kf >> 2, ci0 = (kf & 3) * 32;
            int colb = (ci0 + lhi * 8) * 2;
            short8v afr[4];
            #pragma unroll
            for (int j = 0; j < 4; ++j) {
                int row = (tb + j) * 16 + l15 + k;
                afr[j] = *(const short8v*)(h2b + ((row * 256 + colb) ^ ((row & 7) << 4)));
            }
            #pragma unroll
            for (int c4 = 0; c4 < 4; ++c4) {
                int ctg = wv_c * 4 + c4;
                size_t foff = ((size_t)(ctg * 12 + kf) * 64 + lane) * 8;
                short8v bh = *(const short8v*)(Wq3h + foff);
                short8v bl = *(const short8v*)(Wq3l + foff);
                #pragma unroll
                for (int j = 0; j < 4; ++j) {
                    acc[c4][j] = MFMA16(afr[j], bh, acc[c4][j]);
                    acc[c4][j] = MFMA16(afr[j], bl, acc[c4][j]);
                }
            }
        }
        short* msrow = ms + (size_t)n * 3328;
        #pragma unroll
        for (int c4 = 0; c4 < 4; ++c4) {
            int ctg = wv_c * 4 + c4;
            int co = ctg * 16 + l15;
            float a3v = A3c[co], c3v = C3c[co];
            float s16[4]; float h64 = 0.f;
            #pragma unroll
            for (int j = 0; j < 4; ++j) {
                float s = 0.f;
                #pragma unroll
                for (int r = 0; r < 4; ++r) {
                    float v = fmaf(a3v, acc[c4][j][r], c3v);
                    v = LRELU(v);
                    s += v;
                }
                s += __shfl_xor(s, 16);
                s += __shfl_xor(s, 32);
                s16[j] = s; h64 += s;
            }
            if (lane < 16) {
                #pragma unroll
                for (int j = 0; j < 4; ++j)
                    msrow[co * 8 + tb + j] = (short)f2bf(s16[j] * (1.f / 16.f));
                msrow[2048 + co * 4 + wv_t * 2 + 0] = (short)f2bf((s16[0] + s16[1]) * (1.f / 32.f));
                msrow[2048 + co * 4 + wv_t * 2 + 1] = (short)f2bf((s16[2] + s16[3]) * (1.f / 32.f));
                gsum[wv_t * 256 + co] = h64;
            }
        }
        __syncthreads();
        if (wv_t == 0 && lane < 16) {
            #pragma unroll
            for (int c4 = 0; c4 < 4; ++c4) {
                int co = (wv_c * 4 + c4) * 16 + l15;
                float g = gsum[co] + gsum[256 + co];
                msrow[3072 + co] = (short)f2bf(g * (1.f / 128.f));
            }
        }
    }
}

// ---------------------------------------------------------------------------
// gemm1 split-K: P[kk][1024][512] f32 partials, no bias/act.
// Block 64n x 64m, 4 waves of 32n x 32m, K chunk = 832.
// ---------------------------------------------------------------------------
__global__ __launch_bounds__(256) void gemm1_splitk(
    const short* __restrict__ Wh, const short* __restrict__ Wl,
    const short* __restrict__ Act, float* __restrict__ P)
{
    const int K = 3328, KCHUNK = 832;
    const int tid = threadIdx.x;
    const int w = tid >> 6, lane = tid & 63;
    const int l15 = lane & 15, lhi = lane >> 4;
    const int n0 = blockIdx.x * 64 + (w & 1) * 32;
    const int m0 = blockIdx.y * 64 + (w >> 1) * 32;
    const int kbeg = blockIdx.z * KCHUNK;

    f32x4 acc[2][2];
    #pragma unroll
    for (int i = 0; i < 2; ++i)
        #pragma unroll
        for (int j = 0; j < 2; ++j) acc[i][j] = (f32x4){0.f, 0.f, 0.f, 0.f};

    const short* aw0 = Wh + (size_t)(n0 + l15) * K + kbeg + lhi * 8;
    const short* aw1 = aw0 + 16 * K;
    const short* av0 = Wl + (size_t)(n0 + l15) * K + kbeg + lhi * 8;
    const short* av1 = av0 + 16 * K;
    const short* bp0 = Act + (size_t)(m0 + l15) * K + kbeg + lhi * 8;
    const short* bp1 = bp0 + 16 * K;

    #pragma unroll 4
    for (int k0 = 0; k0 < KCHUNK; k0 += 32) {
        short8v b0 = *(const short8v*)(bp0 + k0);
        short8v b1 = *(const short8v*)(bp1 + k0);
        short8v a0h = *(const short8v*)(aw0 + k0);
        short8v a1h = *(const short8v*)(aw1 + k0);
        short8v a0l = *(const short8v*)(av0 + k0);
        short8v a1l = *(const short8v*)(av1 + k0);
        acc[0][0] = MFMA16(a0h, b0, acc[0][0]); acc[0][0] = MFMA16(a0l, b0, acc[0][0]);
        acc[0][1] = MFMA16(a0h, b1, acc[0][1]); acc[0][1] = MFMA16(a0l, b1, acc[0][1]);
        acc[1][0] = MFMA16(a1h, b0, acc[1][0]); acc[1][0] = MFMA16(a1l, b0, acc[1][0]);
        acc[1][1] = MFMA16(a1h, b1, acc[1][1]); acc[1][1] = MFMA16(a1l, b1, acc[1][1]);
    }

    float* Pk = P + (size_t)blockIdx.z * (1024 * 512);
    #pragma unroll
    for (int ni = 0; ni < 2; ++ni) {
        int nb = n0 + ni * 16 + lhi * 4;
        #pragma unroll
        for (int mi = 0; mi < 2; ++mi) {
            int m = m0 + mi * 16 + l15;
            *(f32x4*)(Pk + (size_t)m * 512 + nb) = acc[ni][mi];
        }
    }
}

// Combine split-K partials: sum 4 planes + bias + relu -> bf16 h2l.
__global__ __launch_bounds__(256) void combine_h2(
    const float* __restrict__ P, const float* __restrict__ bias,
    short* __restrict__ h2l)
{
    int i4 = blockIdx.x * 256 + threadIdx.x;     // 0..131071, 4 floats each
    const f32x4* p = (const f32x4*)P;
    f32x4 s0 = p[i4], s1 = p[i4 + 131072], s2 = p[i4 + 262144], s3 = p[i4 + 393216];
    int nb = (i4 * 4) & 511;
    f32x4 b = *(const f32x4*)(bias + nb);
    short4v pk;
    #pragma unroll
    for (int r = 0; r < 4; ++r) {
        float v = s0[r] + s1[r] + s2[r] + s3[r] + b[r];
        v = v > 0.f ? v : 0.f;
        pk[r] = (short)f2bf(v);
    }
    *(short4v*)(h2l + (size_t)i4 * 4) = pk;
}

// ---------------------------------------------------------------------------
// gemm2: out[1024][256] f32 = h2l[1024][512] x lw2^T + lb2.
// Block 32n x 32m, 4 waves of 16n x 16m. 256 blocks.
// ---------------------------------------------------------------------------
__global__ __launch_bounds__(256) void gemm2_kernel(
    const short* __restrict__ Wh, const short* __restrict__ Wl,
    const short* __restrict__ Act, const float* __restrict__ bias,
    float* __restrict__ out)
{
    const int K = 512;
    const int tid = threadIdx.x;
    const int w = tid >> 6, lane = tid & 63;
    const int l15 = lane & 15, lhi = lane >> 4;
    const int n0 = blockIdx.x * 32 + (w & 1) * 16;
    const int m0 = blockIdx.y * 32 + (w >> 1) * 16;

    f32x4 acc = (f32x4){0.f, 0.f, 0.f, 0.f};
    const short* awh = Wh + (size_t)(n0 + l15) * K + lhi * 8;
    const short* awl = Wl + (size_t)(n0 + l15) * K + lhi * 8;
    const short* bp  = Act + (size_t)(m0 + l15) * K + lhi * 8;

    #pragma unroll 4
    for (int k0 = 0; k0 < K; k0 += 32) {
        short8v b  = *(const short8v*)(bp + k0);
        short8v ah = *(const short8v*)(awh + k0);
        short8v al = *(const short8v*)(awl + k0);
        acc = MFMA16(ah, b, acc);
        acc = MFMA16(al, b, acc);
    }

    f32x4 bs = *(const f32x4*)(bias + n0 + lhi * 4);
    f32x4 vv;
    #pragma unroll
    for (int r = 0; r < 4; ++r) vv[r] = acc[r] + bs[r];
    *(f32x4*)(out + (size_t)(m0 + l15) * 256 + n0 + lhi * 4) = vv;
}

extern "C" void kernel_launch(void* const* d_in, const int* in_sizes, int n_in,
                              void* d_out, int out_size, void* d_ws, size_t ws_size,
                              hipStream_t stream) {
    int I_x, I_w1, I_b1, I_w2, I_b2, I_w3, I_b3;
    int I_g1, I_be1, I_m1, I_v1, I_g2, I_be2, I_m2, I_v2, I_g3, I_be3, I_m3, I_v3;
    int I_lw1, I_lb1, I_lw2, I_lb2;
    if (in_sizes[3] == 24576) {
        I_x=0; I_w1=1; I_b1=2; I_w2=3; I_b2=4; I_w3=5; I_b3=6;
        I_g1=7; I_be1=8; I_m1=9; I_v1=10; I_g2=11; I_be2=12; I_m2=13; I_v2=14;
        I_g3=15; I_be3=16; I_m3=17; I_v3=18; I_lw1=19; I_lb1=20; I_lw2=21; I_lb2=22;
    } else {
        I_x=0; I_w1=1; I_b1=2; I_g1=3; I_be1=4; I_m1=5; I_v1=6;
        I_w2=7; I_b2=8; I_g2=9; I_be2=10; I_m2=11; I_v2=12;
        I_w3=13; I_b3=14; I_g3=15; I_be3=16; I_m3=17; I_v3=18;
        I_lw1=19; I_lb1=20; I_lw2=21; I_lb2=22;
    }

    const float* x   = (const float*)d_in[I_x];
    const float* w1  = (const float*)d_in[I_w1];
    const float* b1  = (const float*)d_in[I_b1];
    const float* w2  = (const float*)d_in[I_w2];
    const float* b2  = (const float*)d_in[I_b2];
    const float* w3  = (const float*)d_in[I_w3];
    const float* b3  = (const float*)d_in[I_b3];
    const float* g1  = (const float*)d_in[I_g1];
    const float* be1 = (const float*)d_in[I_be1];
    const float* m1  = (const float*)d_in[I_m1];
    const float* v1  = (const float*)d_in[I_v1];
    const float* g2  = (const float*)d_in[I_g2];
    const float* be2 = (const float*)d_in[I_be2];
    const float* m2  = (const float*)d_in[I_m2];
    const float* v2  = (const float*)d_in[I_v2];
    const float* g3  = (const float*)d_in[I_g3];
    const float* be3 = (const float*)d_in[I_be3];
    const float* m3  = (const float*)d_in[I_m3];
    const float* v3  = (const float*)d_in[I_v3];
    const float* lw1 = (const float*)d_in[I_lw1];
    const float* lb1 = (const float*)d_in[I_lb1];
    const float* lw2 = (const float*)d_in[I_lw2];
    const float* lb2 = (const float*)d_in[I_lb2];

    char* wsb = (char*)d_ws;
    short* ms   = (short*)(wsb);                 // 1024*3328*2 = 6,815,744
    short* h2l  = (short*)(wsb + 6815744);       // 1024*512*2  = 1,048,576
    short* Wf2h = (short*)(wsb + 7864320);       // 24576*2
    short* Wf2l = (short*)(wsb + 7913472);
    short* Wq3h = (short*)(wsb + 7962624);       // 98304*2
    short* Wq3l = (short*)(wsb + 8159232);
    short* lw1h = (short*)(wsb + 8355840);       // 1703936*2
    short* lw1l = (short*)(wsb + 11763712);
    short* lw2h = (short*)(wsb + 15171584);      // 131072*2
    short* lw2l = (short*)(wsb + 15433728);
    float* P    = (float*)(wsb + 15695872);      // 4*1024*512*4 = 8,388,608 -> end 24,084,480

    prep_weights<<<2048, 256, 0, stream>>>(w2, w3, lw1, lw2,
        Wf2h, Wf2l, Wq3h, Wq3l, lw1h, lw1l, lw2h, lw2l);

    conv_fused_mfma<<<1024, 512, 0, stream>>>(
        x, w1, b1, g1, be1, m1, v1, b2, g2, be2, m2, v2,
        b3, g3, be3, m3, v3, Wf2h, Wf2l, Wq3h, Wq3l, ms);

    gemm1_splitk<<<dim3(8, 16, 4), 256, 0, stream>>>(lw1h, lw1l, ms, P);
    combine_h2<<<512, 256, 0, stream>>>(P, lb1, h2l);
    gemm2_kernel<<<dim3(8, 32), 256, 0, stream>>>(lw2h, lw2l, h2l, lb2, (float*)d_out);
}